// Round 4
// baseline (1170.512 us; speedup 1.0000x reference)
//
#include <hip/hip_runtime.h>

#define HW   (256*256)        // 65536
#define VOL  (64*HW)          // 4194304 per batch volume
#define NTOT (4ull*VOL)
#define C1v  1e-4f
#define C2v  9e-4f
#define EPSv 1e-8f

typedef float    f2 __attribute__((ext_vector_type(2)));
typedef _Float16 h2 __attribute__((ext_vector_type(2)));

// ws layout:
// [0      .. 63]     : w[11] float (1D separable weights)
// [64     .. 8255]   : partials[1024] double
// [16640  .. ]       : field volumes fp16: 5*VOL*2 bytes per resident batch

__global__ void init_weights(const float* __restrict__ k3, float* __restrict__ w) {
    int i = threadIdx.x;
    if (i < 11) {
        float s = 0.f;
        for (int t = 0; t < 121; ++t) s += k3[i * 121 + t];
        w[i] = s;   // k3 is separable: row-sum = 1D weight
    }
}

// Pass 1: products + W-conv (fp32, float2-interleaved LDS) + H-conv (packed fp16),
// writes 5 blurred fields as fp16.  grid: (4, 16, 64*nb) x 256.
__global__ __launch_bounds__(256) void blur_hw(
    const float* __restrict__ x, const float* __restrict__ y,
    const float* __restrict__ w11, _Float16* __restrict__ fields, int b0)
{
    __shared__ f2 sxy[26][74];            // 15,392 B
    __shared__ _Float16 tf[5][26][64];    // 16,640 B  -> 32 KB total

    const int d   = blockIdx.z & 63;
    const int bz  = blockIdx.z >> 6;
    const int h0  = blockIdx.y * 16;
    const int w0  = blockIdx.x * 64;
    const int tid = threadIdx.x;

    float wl[11];
#pragma unroll
    for (int t = 0; t < 11; ++t) wl[t] = w11[t];

    const float* xb = x + (size_t)(b0 + bz) * VOL + (size_t)d * HW;
    const float* yb = y + (size_t)(b0 + bz) * VOL + (size_t)d * HW;

    for (int p = tid; p < 26 * 74; p += 256) {
        int r = p / 74, c = p - r * 74;
        int gh = h0 - 5 + r, gw = w0 - 5 + c;
        f2 v = {0.f, 0.f};
        if ((unsigned)gh < 256u && (unsigned)gw < 256u) {
            v.x = xb[gh * 256 + gw];
            v.y = yb[gh * 256 + gw];
        }
        sxy[r][c] = v;
    }
    __syncthreads();

    for (int p = tid; p < 26 * 64; p += 256) {
        int r = p >> 6, c = p & 63;
        float aX = 0, aY = 0, aXX = 0, aYY = 0, aXY = 0;
#pragma unroll
        for (int k = 0; k < 11; ++k) {
            f2 v = sxy[r][c + k];
            float wk = wl[k];
            aX  += wk * v.x;
            aY  += wk * v.y;
            aXX += wk * (v.x * v.x);
            aYY += wk * (v.y * v.y);
            aXY += wk * (v.x * v.y);
        }
        tf[0][r][c] = (_Float16)aX;
        tf[1][r][c] = (_Float16)aY;
        tf[2][r][c] = (_Float16)aXX;
        tf[3][r][c] = (_Float16)aYY;
        tf[4][r][c] = (_Float16)aXY;
    }
    __syncthreads();

    h2 wl2[11];
#pragma unroll
    for (int t = 0; t < 11; ++t) { _Float16 h = (_Float16)wl[t]; wl2[t] = (h2){h, h}; }

    _Float16* fb = fields + (size_t)bz * 5 * VOL + (size_t)d * HW;

#pragma unroll
    for (int i = 0; i < 2; ++i) {
        int p = tid + i * 256;
        int r = p >> 5, c2 = p & 31;
        h2 o0 = {0,0}, o1 = {0,0}, o2 = {0,0}, o3 = {0,0}, o4 = {0,0};
#pragma unroll
        for (int j = 0; j < 11; ++j) {
            h2 w2 = wl2[j];
            o0 += w2 * *(const h2*)&tf[0][r + j][2 * c2];
            o1 += w2 * *(const h2*)&tf[1][r + j][2 * c2];
            o2 += w2 * *(const h2*)&tf[2][r + j][2 * c2];
            o3 += w2 * *(const h2*)&tf[3][r + j][2 * c2];
            o4 += w2 * *(const h2*)&tf[4][r + j][2 * c2];
        }
        size_t oi = (size_t)(h0 + r) * 256 + (w0 + 2 * c2);
        *(h2*)&fb[oi]                   = o0;
        *(h2*)&fb[(size_t)VOL + oi]     = o1;
        *(h2*)&fb[2 * (size_t)VOL + oi] = o2;
        *(h2*)&fb[3 * (size_t)VOL + oi] = o3;
        *(h2*)&fb[4 * (size_t)VOL + oi] = o4;
    }
}

// Pass 2: D-conv via fp32 float2 register rings + SSIM + reduction.
// DHALF templated so ALL loop control flow is compile-time (rings stay in VGPRs).
// grid: (128, nb) x 256.  Thread owns one column pair for D-rows [DHALF*32, DHALF*32+32).
template<int DHALF>
__global__ __launch_bounds__(256) void dconv_ssim(
    const _Float16* __restrict__ fields, const float* __restrict__ w11,
    double* __restrict__ partials, int b0)
{
    const int pr = blockIdx.x * 256 + threadIdx.x;  // pair index 0..32767
    const int bz = blockIdx.y;

    float wl[11];
#pragma unroll
    for (int t = 0; t < 11; ++t) wl[t] = w11[t];

    const h2* fX  = (const h2*)(fields + (size_t)bz * 5 * VOL);
    const h2* fY  = fX + (size_t)VOL / 2;
    const h2* fXX = fX + (size_t)VOL;
    const h2* fYY = fX + 3 * (size_t)VOL / 2;
    const h2* fXY = fX + 2 * (size_t)VOL;

    f2 rX[11], rY[11], rXX[11], rYY[11], rXY[11];
#pragma unroll
    for (int t = 0; t < 11; ++t) {
        rX[t] = (f2){0,0}; rY[t] = (f2){0,0};
        rXX[t] = (f2){0,0}; rYY[t] = (f2){0,0}; rXY[t] = (f2){0,0};
    }

    float acc = 0.f;

#pragma unroll
    for (int s = 0; s < 42; ++s) {
        const int dd = DHALF * 32 - 5 + s;          // compile-time after unroll
        const int slot = s % 11;                    // compile-time
        if (dd >= 0 && dd < 64) {                   // compile-time
            size_t idx = (size_t)dd * (HW / 2) + pr;
            rX[slot]  = __builtin_convertvector(fX[idx],  f2);
            rY[slot]  = __builtin_convertvector(fY[idx],  f2);
            rXX[slot] = __builtin_convertvector(fXX[idx], f2);
            rYY[slot] = __builtin_convertvector(fYY[idx], f2);
            rXY[slot] = __builtin_convertvector(fXY[idx], f2);
        } else {
            rX[slot]  = (f2){0,0}; rY[slot]  = (f2){0,0};
            rXX[slot] = (f2){0,0}; rYY[slot] = (f2){0,0}; rXY[slot] = (f2){0,0};
        }

        if (s >= 10) {                              // compile-time; output depth DHALF*32 + s-10
            f2 mX = {0,0}, mY = {0,0}, cXX = {0,0}, cYY = {0,0}, cXY = {0,0};
#pragma unroll
            for (int t = 0; t < 11; ++t) {
                const int j = (s + 1 + t) % 11;     // compile-time
                float wt = wl[t];
                mX  += wt * rX[j];
                mY  += wt * rY[j];
                cXX += wt * rXX[j];
                cYY += wt * rYY[j];
                cXY += wt * rXY[j];
            }
#pragma unroll
            for (int l = 0; l < 2; ++l) {
                float mx = mX[l],  my = mY[l];
                float xx = cXX[l], yy = cYY[l], xy = cXY[l];
                float mx2 = mx * mx, my2 = my * my, mxy = mx * my;
                float sx2 = xx - mx2, sy2 = yy - my2, sxy = xy - mxy;
                float num = (2.f * mxy + C1v) * (2.f * sxy + C2v);
                float den = (mx2 + my2 + C1v) * (sx2 + sy2 + C2v);
                acc += num * __builtin_amdgcn_rcpf(den + EPSv);
            }
        }
    }

    for (int off = 32; off; off >>= 1) acc += __shfl_down(acc, off, 64);
    __shared__ float wsum[4];
    int lane = threadIdx.x & 63, wid = threadIdx.x >> 6;
    if (lane == 0) wsum[wid] = acc;
    __syncthreads();
    if (threadIdx.x == 0) {
        float ssum = wsum[0] + wsum[1] + wsum[2] + wsum[3];
        partials[blockIdx.x + 128 * DHALF + 256 * (b0 + bz)] = (double)ssum;
    }
}

__global__ void finalize(const double* __restrict__ partials, float* __restrict__ out, int n) {
    __shared__ double sh[256];
    double s = 0.0;
    for (int i = threadIdx.x; i < n; i += 256) s += partials[i];
    sh[threadIdx.x] = s;
    __syncthreads();
    for (int stride = 128; stride; stride >>= 1) {
        if (threadIdx.x < stride) sh[threadIdx.x] += sh[threadIdx.x + stride];
        __syncthreads();
    }
    if (threadIdx.x == 0) out[0] = 1.0f - (float)(sh[0] / (double)NTOT);
}

extern "C" void kernel_launch(void* const* d_in, const int* in_sizes, int n_in,
                              void* d_out, int out_size, void* d_ws, size_t ws_size,
                              hipStream_t stream) {
    const float* x  = (const float*)d_in[0];
    const float* y  = (const float*)d_in[1];
    const float* k3 = (const float*)d_in[2];
    float* out = (float*)d_out;

    char* ws = (char*)d_ws;
    float*     w11      = (float*)ws;
    double*    partials = (double*)(ws + 64);
    _Float16*  fields   = (_Float16*)(ws + 16640);

    const size_t perBatch = (size_t)5 * VOL * 2;   // fp16 fields per batch
    const bool all4 = ws_size >= 16640 + 4 * perBatch;

    init_weights<<<1, 64, 0, stream>>>(k3, w11);

    if (all4) {
        blur_hw      <<<dim3(4, 16, 256), 256, 0, stream>>>(x, y, w11, fields, 0);
        dconv_ssim<0><<<dim3(128, 4),     256, 0, stream>>>(fields, w11, partials, 0);
        dconv_ssim<1><<<dim3(128, 4),     256, 0, stream>>>(fields, w11, partials, 0);
    } else {
        for (int b = 0; b < 4; ++b) {
            blur_hw      <<<dim3(4, 16, 64), 256, 0, stream>>>(x, y, w11, fields, b);
            dconv_ssim<0><<<dim3(128, 1),    256, 0, stream>>>(fields, w11, partials, b);
            dconv_ssim<1><<<dim3(128, 1),    256, 0, stream>>>(fields, w11, partials, b);
        }
    }

    finalize<<<1, 256, 0, stream>>>(partials, out, 1024);
}

// Round 5
// 239.658 us; speedup vs baseline: 4.8841x; 4.8841x over previous
//
#include <hip/hip_runtime.h>

#define HW   (256*256)        // 65536
#define VOL  (64*HW)          // 4194304 per batch volume
#define NTOT (4ull*VOL)
#define C1v  1e-4f
#define C2v  9e-4f
#define EPSv 1e-8f

typedef float    f2 __attribute__((ext_vector_type(2)));
typedef _Float16 h2 __attribute__((ext_vector_type(2)));

// ws layout:
// [0      .. 63]     : w[11] float (1D separable weights)
// [64     .. 8255]   : partials[1024] double
// [16640  .. ]       : field volumes fp16: 5*VOL*2 bytes per resident batch

__global__ void init_weights(const float* __restrict__ k3, float* __restrict__ w) {
    int i = threadIdx.x;
    if (i < 11) {
        float s = 0.f;
        for (int t = 0; t < 121; ++t) s += k3[i * 121 + t];
        w[i] = s;   // k3 is separable: row-sum = 1D weight
    }
}

// Pass 1: products + W-conv (fp32, float2-interleaved LDS) + H-conv (packed fp16),
// writes 5 blurred fields as fp16.  grid: (4, 16, 64*nb) x 256.
__global__ __launch_bounds__(256) void blur_hw(
    const float* __restrict__ x, const float* __restrict__ y,
    const float* __restrict__ w11, _Float16* __restrict__ fields, int b0)
{
    __shared__ f2 sxy[26][74];            // 15,392 B
    __shared__ _Float16 tf[5][26][64];    // 16,640 B  -> 32 KB total

    const int d   = blockIdx.z & 63;
    const int bz  = blockIdx.z >> 6;
    const int h0  = blockIdx.y * 16;
    const int w0  = blockIdx.x * 64;
    const int tid = threadIdx.x;

    float wl[11];
#pragma unroll
    for (int t = 0; t < 11; ++t) wl[t] = w11[t];

    const float* xb = x + (size_t)(b0 + bz) * VOL + (size_t)d * HW;
    const float* yb = y + (size_t)(b0 + bz) * VOL + (size_t)d * HW;

    for (int p = tid; p < 26 * 74; p += 256) {
        int r = p / 74, c = p - r * 74;
        int gh = h0 - 5 + r, gw = w0 - 5 + c;
        f2 v = {0.f, 0.f};
        if ((unsigned)gh < 256u && (unsigned)gw < 256u) {
            v.x = xb[gh * 256 + gw];
            v.y = yb[gh * 256 + gw];
        }
        sxy[r][c] = v;
    }
    __syncthreads();

    for (int p = tid; p < 26 * 64; p += 256) {
        int r = p >> 6, c = p & 63;
        float aX = 0, aY = 0, aXX = 0, aYY = 0, aXY = 0;
#pragma unroll
        for (int k = 0; k < 11; ++k) {
            f2 v = sxy[r][c + k];
            float wk = wl[k];
            aX  += wk * v.x;
            aY  += wk * v.y;
            aXX += wk * (v.x * v.x);
            aYY += wk * (v.y * v.y);
            aXY += wk * (v.x * v.y);
        }
        tf[0][r][c] = (_Float16)aX;
        tf[1][r][c] = (_Float16)aY;
        tf[2][r][c] = (_Float16)aXX;
        tf[3][r][c] = (_Float16)aYY;
        tf[4][r][c] = (_Float16)aXY;
    }
    __syncthreads();

    h2 wl2[11];
#pragma unroll
    for (int t = 0; t < 11; ++t) { _Float16 h = (_Float16)wl[t]; wl2[t] = (h2){h, h}; }

    _Float16* fb = fields + (size_t)bz * 5 * VOL + (size_t)d * HW;

#pragma unroll
    for (int i = 0; i < 2; ++i) {
        int p = tid + i * 256;
        int r = p >> 5, c2 = p & 31;
        h2 o0 = {0,0}, o1 = {0,0}, o2 = {0,0}, o3 = {0,0}, o4 = {0,0};
#pragma unroll
        for (int j = 0; j < 11; ++j) {
            h2 w2 = wl2[j];
            o0 += w2 * *(const h2*)&tf[0][r + j][2 * c2];
            o1 += w2 * *(const h2*)&tf[1][r + j][2 * c2];
            o2 += w2 * *(const h2*)&tf[2][r + j][2 * c2];
            o3 += w2 * *(const h2*)&tf[3][r + j][2 * c2];
            o4 += w2 * *(const h2*)&tf[4][r + j][2 * c2];
        }
        size_t oi = (size_t)(h0 + r) * 256 + (w0 + 2 * c2);
        *(h2*)&fb[oi]                   = o0;
        *(h2*)&fb[(size_t)VOL + oi]     = o1;
        *(h2*)&fb[2 * (size_t)VOL + oi] = o2;
        *(h2*)&fb[3 * (size_t)VOL + oi] = o3;
        *(h2*)&fb[4 * (size_t)VOL + oi] = o4;
    }
}

// Pass 2: D-conv via SCALAR fp32 register rings (round-1 structure) + SSIM + reduction.
// grid: (256, nb) x 256.  One thread per column, 69 steps, all guards compile-time.
__global__ __launch_bounds__(256) void dconv_ssim(
    const _Float16* __restrict__ fields, const float* __restrict__ w11,
    double* __restrict__ partials, int b0)
{
    const int col = blockIdx.x * 256 + threadIdx.x;  // 0..65535 within slice
    const int bz  = blockIdx.y;

    float wl[11];
#pragma unroll
    for (int t = 0; t < 11; ++t) wl[t] = w11[t];

    const _Float16* fX  = fields + (size_t)bz * 5 * VOL;
    const _Float16* fY  = fX + (size_t)VOL;
    const _Float16* fXX = fX + 2 * (size_t)VOL;
    const _Float16* fYY = fX + 3 * (size_t)VOL;
    const _Float16* fXY = fX + 4 * (size_t)VOL;

    float bX[11], bY[11], bXX[11], bYY[11], bXY[11];
#pragma unroll
    for (int t = 0; t < 11; ++t) { bX[t] = 0; bY[t] = 0; bXX[t] = 0; bYY[t] = 0; bXY[t] = 0; }

    float acc = 0.f;
#pragma unroll
    for (int s = 0; s < 69; ++s) {
        const int slot = s % 11;                 // compile-time (full unroll)
        float vX = 0, vY = 0, vXX = 0, vYY = 0, vXY = 0;
        if (s < 64) {                            // compile-time
            size_t idx = (size_t)s * HW + col;
            vX  = (float)fX[idx];
            vY  = (float)fY[idx];
            vXX = (float)fXX[idx];
            vYY = (float)fYY[idx];
            vXY = (float)fXY[idx];
        }
        bX[slot] = vX; bY[slot] = vY; bXX[slot] = vXX; bYY[slot] = vYY; bXY[slot] = vXY;

        if (s >= 5) {                            // compile-time; emit depth s-5
            float mX = 0, mY = 0, cXX = 0, cYY = 0, cXY = 0;
#pragma unroll
            for (int t = 0; t < 11; ++t) {
                const int j = (s + 1 + t) % 11;  // compile-time
                float wt = wl[t];
                mX  += wt * bX[j];
                mY  += wt * bY[j];
                cXX += wt * bXX[j];
                cYY += wt * bYY[j];
                cXY += wt * bXY[j];
            }
            float mx2 = mX * mX, my2 = mY * mY, mxy = mX * mY;
            float sx2 = cXX - mx2, sy2 = cYY - my2, sxy = cXY - mxy;
            float num = (2.f * mxy + C1v) * (2.f * sxy + C2v);
            float den = (mx2 + my2 + C1v) * (sx2 + sy2 + C2v);
            acc += num * __builtin_amdgcn_rcpf(den + EPSv);
        }
    }

    // reduce 256 threads -> one partial per block (deterministic)
    for (int off = 32; off; off >>= 1) acc += __shfl_down(acc, off, 64);
    __shared__ float wsum[4];
    int lane = threadIdx.x & 63, wid = threadIdx.x >> 6;
    if (lane == 0) wsum[wid] = acc;
    __syncthreads();
    if (threadIdx.x == 0) {
        float s = wsum[0] + wsum[1] + wsum[2] + wsum[3];
        partials[(size_t)(b0 + bz) * 256 + blockIdx.x] = (double)s;
    }
}

__global__ void finalize(const double* __restrict__ partials, float* __restrict__ out, int n) {
    __shared__ double sh[256];
    double s = 0.0;
    for (int i = threadIdx.x; i < n; i += 256) s += partials[i];
    sh[threadIdx.x] = s;
    __syncthreads();
    for (int stride = 128; stride; stride >>= 1) {
        if (threadIdx.x < stride) sh[threadIdx.x] += sh[threadIdx.x + stride];
        __syncthreads();
    }
    if (threadIdx.x == 0) out[0] = 1.0f - (float)(sh[0] / (double)NTOT);
}

extern "C" void kernel_launch(void* const* d_in, const int* in_sizes, int n_in,
                              void* d_out, int out_size, void* d_ws, size_t ws_size,
                              hipStream_t stream) {
    const float* x  = (const float*)d_in[0];
    const float* y  = (const float*)d_in[1];
    const float* k3 = (const float*)d_in[2];
    float* out = (float*)d_out;

    char* ws = (char*)d_ws;
    float*     w11      = (float*)ws;
    double*    partials = (double*)(ws + 64);
    _Float16*  fields   = (_Float16*)(ws + 16640);

    const size_t perBatch = (size_t)5 * VOL * 2;   // fp16 fields per batch
    const bool all4 = ws_size >= 16640 + 4 * perBatch;

    init_weights<<<1, 64, 0, stream>>>(k3, w11);

    if (all4) {
        blur_hw   <<<dim3(4, 16, 256), 256, 0, stream>>>(x, y, w11, fields, 0);
        dconv_ssim<<<dim3(256, 4),     256, 0, stream>>>(fields, w11, partials, 0);
    } else {
        for (int b = 0; b < 4; ++b) {
            blur_hw   <<<dim3(4, 16, 64), 256, 0, stream>>>(x, y, w11, fields, b);
            dconv_ssim<<<dim3(256, 1),    256, 0, stream>>>(fields, w11, partials, b);
        }
    }

    finalize<<<1, 256, 0, stream>>>(partials, out, 1024);
}